// Round 1
// baseline (326.526 us; speedup 1.0000x reference)
//
#include <hip/hip_runtime.h>
#include <hip/hip_cooperative_groups.h>

namespace cg = cooperative_groups;

#define N_NODES 100000
#define N_EDGES 1600000
#define D 64

#define BN 64                               // nodes per bucket
#define NBUCK ((N_NODES + BN - 1) / BN)     // 1563
#define CHW 256                             // coarse chunks (blocks)
#define CH ((N_EDGES + CHW - 1) / CHW)      // 6250 edges per chunk
#define CITER 13                            // ceil(CH/512)
#define SMAX 2048                           // LDS edge capacity per bucket (mean 1024)
#define OVF 512                             // overflow list (never used in practice)
#define PAD 16                              // cursor padding (64 B) -> per-line atomics

static __device__ __forceinline__ unsigned short f2bf(float f) {
    unsigned u = __float_as_uint(f);
    u += 0x7FFFu + ((u >> 16) & 1u);
    return (unsigned short)(u >> 16);
}
static __device__ __forceinline__ float bf2f(unsigned short h) {
    return __uint_as_float((unsigned)h << 16);
}

// ---------------- GEMM: support(bf16) = X @ W ----------------
__global__ __launch_bounds__(256) void gcn_gemm(const float* __restrict__ x,
                                                const float* __restrict__ w,
                                                unsigned short* __restrict__ support) {
    __shared__ float4 wsh[64 * 16];
    int tid = threadIdx.x;
    const float4* w4 = (const float4*)w;
    for (int i = tid; i < 64 * 16; i += 256) wsh[i] = w4[i];
    __syncthreads();

    int idx = blockIdx.x * 256 + tid;
    int rowpair = idx >> 4;
    int c4 = idx & 15;
    long r0 = (long)rowpair * 2;
    const float4* xr0 = (const float4*)(x + r0 * D);
    const float4* xr1 = (const float4*)(x + (r0 + 1) * D);

    float4 a0 = make_float4(0.f, 0.f, 0.f, 0.f);
    float4 a1 = make_float4(0.f, 0.f, 0.f, 0.f);
    #pragma unroll 4
    for (int k4 = 0; k4 < 16; ++k4) {
        float4 xv0 = xr0[k4];
        float4 xv1 = xr1[k4];
        float4 w0 = wsh[(4 * k4 + 0) * 16 + c4];
        float4 w1 = wsh[(4 * k4 + 1) * 16 + c4];
        float4 w2 = wsh[(4 * k4 + 2) * 16 + c4];
        float4 w3 = wsh[(4 * k4 + 3) * 16 + c4];
        a0 += w0 * xv0.x + w1 * xv0.y + w2 * xv0.z + w3 * xv0.w;
        a1 += w0 * xv1.x + w1 * xv1.y + w2 * xv1.z + w3 * xv1.w;
    }
    ushort4* s4 = (ushort4*)support;
    s4[r0 * 16 + c4] = make_ushort4(f2bf(a0.x), f2bf(a0.y), f2bf(a0.z), f2bf(a0.w));
    s4[(r0 + 1) * 16 + c4] = make_ushort4(f2bf(a1.x), f2bf(a1.y), f2bf(a1.z), f2bf(a1.w));
}

// ---------------- cooperative: count (node+bucket) -> scan -> reserve -> scatter ----
// Replaces bcount + bscan + coarse. Edges staged in regs once; node-level counts
// (ncnt) produced here so bgather's phase-A recount disappears.
__global__ __launch_bounds__(512, 2) void gcn_bin(const int* __restrict__ src,
                                                  const int* __restrict__ dst,
                                                  const float* __restrict__ adj,
                                                  int* __restrict__ ncnt,
                                                  int* __restrict__ btot,
                                                  int* __restrict__ sbase,
                                                  int* __restrict__ gcur,
                                                  int2* __restrict__ coarse) {
    __shared__ int h[NBUCK];
    __shared__ int cur[NBUCK];
    __shared__ int psc[512];
    int tid = threadIdx.x, w = blockIdx.x;
    for (int i = tid; i < NBUCK; i += 512) h[i] = 0;
    __syncthreads();

    // phase 1: stage chunk in regs, per-node global hist + per-bucket LDS hist
    int e0 = w * CH, e1 = min(e0 + CH, N_EDGES);
    int dreg[CITER], sreg[CITER];
    float areg[CITER];
    #pragma unroll
    for (int it = 0; it < CITER; ++it) {
        int e = e0 + tid + it * 512;
        dreg[it] = -1;
        if (e < e1) {
            dreg[it] = __builtin_nontemporal_load(&dst[e]);
            sreg[it] = __builtin_nontemporal_load(&src[e]);
            areg[it] = __builtin_nontemporal_load(&adj[e]);
            atomicAdd(&ncnt[dreg[it]], 1);       // device-scope, coherent point
            atomicAdd(&h[dreg[it] >> 6], 1);
        }
    }
    __syncthreads();
    for (int c = tid; c < NBUCK; c += 512)
        if (h[c]) atomicAdd(&btot[c], h[c]);

    cg::this_grid().sync();

    // phase 2: block 0 scans the 1563 bucket totals -> sbase, cursor seeds.
    // Reads via atomicAdd(p,0) and seeds via atomicExch: every cross-block value
    // moves through device-scope atomics (per-XCD L2s are not coherent).
    if (w == 0) {
        int b0 = tid * 4;
        int v0 = (b0     < NBUCK) ? atomicAdd(&btot[b0    ], 0) : 0;
        int v1 = (b0 + 1 < NBUCK) ? atomicAdd(&btot[b0 + 1], 0) : 0;
        int v2 = (b0 + 2 < NBUCK) ? atomicAdd(&btot[b0 + 2], 0) : 0;
        int v3 = (b0 + 3 < NBUCK) ? atomicAdd(&btot[b0 + 3], 0) : 0;
        int s = v0 + v1 + v2 + v3;
        psc[tid] = s;
        __syncthreads();
        for (int off = 1; off < 512; off <<= 1) {
            int t = 0;
            if (tid >= off) t = psc[tid - off];
            __syncthreads();
            if (tid >= off) psc[tid] += t;
            __syncthreads();
        }
        int run = psc[tid] - s;
        if (b0     < NBUCK) { sbase[b0    ] = run; atomicExch(&gcur[(b0    ) * PAD], run); } run += v0;
        if (b0 + 1 < NBUCK) { sbase[b0 + 1] = run; atomicExch(&gcur[(b0 + 1) * PAD], run); } run += v1;
        if (b0 + 2 < NBUCK) { sbase[b0 + 2] = run; atomicExch(&gcur[(b0 + 2) * PAD], run); } run += v2;
        if (b0 + 3 < NBUCK) { sbase[b0 + 3] = run; atomicExch(&gcur[(b0 + 3) * PAD], run); } run += v3;
        if (tid == 511) sbase[NBUCK] = run;      // == N_EDGES
    }

    cg::this_grid().sync();

    // phase 3: per-block run reservation, then scatter staged edges
    for (int c = tid; c < NBUCK; c += 512) {
        int hc = h[c];
        if (hc) cur[c] = atomicAdd(&gcur[c * PAD], hc);
    }
    __syncthreads();

    #pragma unroll
    for (int it = 0; it < CITER; ++it) {
        if (dreg[it] >= 0) {
            int c = dreg[it] >> 6;
            int pos = atomicAdd(&cur[c], 1);
            coarse[pos] = make_int2(sreg[it] | ((dreg[it] & 63) << 17),
                                    __float_as_int(areg[it]));
        }
    }
}

// ---------------- fused: LDS counting sort (counts from ncnt) + wide gather ----------
__global__ __launch_bounds__(256) void gcn_bgather(const unsigned short* __restrict__ support,
                                                   const int2* __restrict__ coarse,
                                                   const int* __restrict__ sbase,
                                                   const int* __restrict__ ncnt,
                                                   const float* __restrict__ bias,
                                                   float* __restrict__ out) {
    __shared__ int2 sE[SMAX];       // 16 KB sorted edges
    __shared__ int2 ovfE[OVF];      // 4 KB overflow (never used in practice)
    __shared__ int cntS[BN], loffS[BN], curS[BN];
    __shared__ int ovfN;

    int tid = threadIdx.x, wv = tid >> 6, lane = tid & 63;
    int b = blockIdx.x;
    int e0 = sbase[b];
    int e1 = sbase[b + 1];

    // counts come straight from gcn_bin's node histogram (phase A eliminated)
    if (tid < BN) {
        int n = b * BN + tid;
        cntS[tid] = (n < N_NODES) ? ncnt[n] : 0;
    }
    if (tid == 0) ovfN = 0;
    __syncthreads();

    // scan 64 counters
    if (tid < BN) loffS[tid] = cntS[tid];
    __syncthreads();
    for (int off = 1; off < BN; off <<= 1) {
        int t = 0;
        if (tid < BN && tid >= off) t = loffS[tid - off];
        __syncthreads();
        if (tid < BN && tid >= off) loffS[tid] += t;
        __syncthreads();
    }
    if (tid < BN) {
        int excl = loffS[tid] - cntS[tid];
        loffS[tid] = excl;
        curS[tid] = excl;
    }
    __syncthreads();

    // phase B: place edges into LDS per-node-sorted (single coarse read)
    for (int e = e0 + tid; e < e1; e += 256) {
        int2 ed = coarse[e];
        int nl = (ed.x >> 17) & 63;
        int pos = atomicAdd(&curS[nl], 1);
        if (pos < SMAX) sE[pos] = ed;
        else {
            int op = atomicAdd(&ovfN, 1);
            if (op < OVF) ovfE[op] = ed;
        }
    }
    __syncthreads();

    // gather: wave wv owns local nodes [wv*16, wv*16+16)
    int eg = lane >> 4;      // edge sub-slot 0..3
    int L  = lane & 15;      // feature quad 0..15
    const uint2* sup2 = (const uint2*)support;     // 8 B = 4 bf16 features
    const float4* bias4 = (const float4*)bias;
    float4* out4 = (float4*)out;
    float4 bv = bias4[L];

    for (int nl = wv * 16; nl < wv * 16 + 16; ++nl) {
        int start = loffS[nl], cnt = cntS[nl];
        int endc = min(start + cnt, SMAX);
        int avail = endc > start ? endc - start : 0;
        float4 acc = make_float4(0.f, 0.f, 0.f, 0.f);
        for (int j = 0; j < avail; j += 16) {
            #pragma unroll
            for (int q = 0; q < 4; ++q) {
                int ei = j + q * 4 + eg;
                int2 ed = sE[start + min(ei, avail - 1)];
                float wgt = (ei < avail) ? __int_as_float(ed.y) : 0.f;
                uint2 p = sup2[(long)(ed.x & 0x1FFFF) * 16 + L];
                acc.x += wgt * __uint_as_float(p.x << 16);
                acc.y += wgt * __uint_as_float(p.x & 0xFFFF0000u);
                acc.z += wgt * __uint_as_float(p.y << 16);
                acc.w += wgt * __uint_as_float(p.y & 0xFFFF0000u);
            }
        }
        // reduce across the 4 edge-slot groups
        acc.x += __shfl_xor(acc.x, 16, 64); acc.y += __shfl_xor(acc.y, 16, 64);
        acc.z += __shfl_xor(acc.z, 16, 64); acc.w += __shfl_xor(acc.w, 16, 64);
        acc.x += __shfl_xor(acc.x, 32, 64); acc.y += __shfl_xor(acc.y, 32, 64);
        acc.z += __shfl_xor(acc.z, 32, 64); acc.w += __shfl_xor(acc.w, 32, 64);
        int n = b * BN + nl;
        if (lane < 16 && n < N_NODES) {
            float4 r = make_float4(acc.x + bv.x, acc.y + bv.y,
                                   acc.z + bv.z, acc.w + bv.w);
            out4[(long)n * 16 + L] = r;
        }
    }

    // overflow fallback (correctness only; never taken for this input)
    __syncthreads();
    int no = min(ovfN, OVF);
    for (int i = wv; i < no; i += 4) {
        int2 ed = ovfE[i];
        int s = ed.x & 0x1FFFF, dl = (ed.x >> 17) & 63;
        int n = b * BN + dl;
        if (n < N_NODES) {
            float v = __int_as_float(ed.y) * bf2f(support[(long)s * D + lane]);
            atomicAdd(&out[(long)n * D + lane], v);
        }
    }
}

extern "C" void kernel_launch(void* const* d_in, const int* in_sizes, int n_in,
                              void* d_out, int out_size, void* d_ws, size_t ws_size,
                              hipStream_t stream) {
    const float* x      = (const float*)d_in[0];
    const float* weight = (const float*)d_in[1];
    const float* bias   = (const float*)d_in[2];
    const float* adj    = (const float*)d_in[3];
    const int*   src    = (const int*)d_in[4];
    const int*   dst    = (const int*)d_in[5];
    float* out = (float*)d_out;

    unsigned short* support = (unsigned short*)d_ws;       // 12,800,000 B
    int2* coarse = (int2*)(support + (long)N_NODES * D);   // 12,800,000 B
    int*  ncnt   = (int*)(coarse + N_EDGES);               // 400,000 B (zeroed)
    int*  btot   = ncnt + N_NODES;                         // 6,252 B   (zeroed)
    int*  sbase  = btot + NBUCK;                           // 6,256 B
    int*  gcur   = sbase + (NBUCK + 1);                    // 100,032 B (seeded in-kernel)

    hipLaunchKernelGGL(gcn_gemm, dim3(N_NODES * 16 / 2 / 256), dim3(256), 0, stream,
                       x, weight, support);
    hipMemsetAsync(ncnt, 0, (N_NODES + NBUCK) * sizeof(int), stream);
    void* args[] = {(void*)&src, (void*)&dst, (void*)&adj, (void*)&ncnt,
                    (void*)&btot, (void*)&sbase, (void*)&gcur, (void*)&coarse};
    hipLaunchCooperativeKernel((void*)gcn_bin, dim3(CHW), dim3(512), args, 0, stream);
    hipLaunchKernelGGL(gcn_bgather, dim3(NBUCK), dim3(256), 0, stream,
                       support, coarse, sbase, ncnt, bias, out);
}

// Round 2
// 173.850 us; speedup vs baseline: 1.8782x; 1.8782x over previous
//
#include <hip/hip_runtime.h>

#define N_NODES 100000
#define N_EDGES 1600000
#define D 64

#define BN 64                               // nodes per bucket
#define NBUCK ((N_NODES + BN - 1) / BN)     // 1563
#define CHW 256                             // binning chunks (blocks)
#define CH ((N_EDGES + CHW - 1) / CHW)      // 6250 edges per chunk
#define CITER 13                            // ceil(CH/512)
#define CAP 2048                            // fixed bucket capacity in coarse
#define SMAX 2048                           // LDS edge capacity (== CAP)
#define PAD 16                              // cursor padding (64 B) -> per-line atomics
#define OVFMAX 32768                        // global overflow list (never used in practice)
#define GEMM_THREADS (N_NODES * 16 / 2)     // 800000: 16 threads per row-pair
#define GEMM_BLKS ((GEMM_THREADS + 511) / 512)  // 1563

static __device__ __forceinline__ unsigned short f2bf(float f) {
    unsigned u = __float_as_uint(f);
    u += 0x7FFFu + ((u >> 16) & 1u);
    return (unsigned short)(u >> 16);
}
static __device__ __forceinline__ float bf2f(unsigned short h) {
    return __uint_as_float((unsigned)h << 16);
}

// ---------------- fused main: blocks [0,CHW) bin edges, blocks [CHW,..) do GEMM ----
// Binning writes into fixed-capacity bucket regions coarse[c*CAP + pos], so no
// bucket-total scan (bcount/bscan) is needed. Roles are independent -> no sync.
__global__ __launch_bounds__(512) void gcn_main(const float* __restrict__ x,
                                                const float* __restrict__ w,
                                                unsigned short* __restrict__ support,
                                                const int* __restrict__ src,
                                                const int* __restrict__ dst,
                                                const float* __restrict__ adj,
                                                int* __restrict__ gcur,
                                                int* __restrict__ ovfcnt,
                                                int4* __restrict__ ovflist,
                                                int2* __restrict__ coarse) {
    __shared__ __align__(16) char smem[16384];
    int tid = threadIdx.x;

    if (blockIdx.x < CHW) {
        // ---- binning role (register-staged chunk, per-block run reservation) ----
        int* h = (int*)smem;            // NBUCK counts
        int* cur = h + NBUCK;           // NBUCK cursors
        int wb = blockIdx.x;
        for (int i = tid; i < NBUCK; i += 512) h[i] = 0;
        __syncthreads();

        int e0 = wb * CH, e1 = min(e0 + CH, N_EDGES);
        int dreg[CITER], sreg[CITER];
        float areg[CITER];
        #pragma unroll
        for (int it = 0; it < CITER; ++it) {
            int e = e0 + tid + it * 512;
            dreg[it] = -1;
            if (e < e1) {
                dreg[it] = __builtin_nontemporal_load(&dst[e]);
                sreg[it] = __builtin_nontemporal_load(&src[e]);
                areg[it] = __builtin_nontemporal_load(&adj[e]);
                atomicAdd(&h[dreg[it] >> 6], 1);
            }
        }
        __syncthreads();

        for (int c = tid; c < NBUCK; c += 512) {
            int hc = h[c];
            if (hc) cur[c] = atomicAdd(&gcur[c * PAD], hc);
        }
        __syncthreads();

        #pragma unroll
        for (int it = 0; it < CITER; ++it) {
            if (dreg[it] >= 0) {
                int c = dreg[it] >> 6;
                int pos = atomicAdd(&cur[c], 1);
                if (pos < CAP) {
                    coarse[c * CAP + pos] =
                        make_int2(sreg[it] | ((dreg[it] & 63) << 17),
                                  __float_as_int(areg[it]));
                } else {
                    int op = atomicAdd(ovfcnt, 1);
                    if (op < OVFMAX)
                        ovflist[op] = make_int4(sreg[it], dreg[it],
                                                __float_as_int(areg[it]), 0);
                }
            }
        }
    } else {
        // ---- GEMM role: support(bf16) = X @ W ----
        float4* wsh = (float4*)smem;    // 64x16 float4 = 16 KB
        const float4* w4 = (const float4*)w;
        for (int i = tid; i < 64 * 16; i += 512) wsh[i] = w4[i];
        __syncthreads();

        int idx = (blockIdx.x - CHW) * 512 + tid;
        if (idx < GEMM_THREADS) {
            int rowpair = idx >> 4;
            int c4 = idx & 15;
            long r0 = (long)rowpair * 2;
            const float4* xr0 = (const float4*)(x + r0 * D);
            const float4* xr1 = (const float4*)(x + (r0 + 1) * D);

            float4 a0 = make_float4(0.f, 0.f, 0.f, 0.f);
            float4 a1 = make_float4(0.f, 0.f, 0.f, 0.f);
            #pragma unroll 4
            for (int k4 = 0; k4 < 16; ++k4) {
                float4 xv0 = xr0[k4];
                float4 xv1 = xr1[k4];
                float4 w0 = wsh[(4 * k4 + 0) * 16 + c4];
                float4 w1 = wsh[(4 * k4 + 1) * 16 + c4];
                float4 w2 = wsh[(4 * k4 + 2) * 16 + c4];
                float4 w3 = wsh[(4 * k4 + 3) * 16 + c4];
                a0 += w0 * xv0.x + w1 * xv0.y + w2 * xv0.z + w3 * xv0.w;
                a1 += w0 * xv1.x + w1 * xv1.y + w2 * xv1.z + w3 * xv1.w;
            }
            ushort4* s4 = (ushort4*)support;
            s4[r0 * 16 + c4] = make_ushort4(f2bf(a0.x), f2bf(a0.y), f2bf(a0.z), f2bf(a0.w));
            s4[(r0 + 1) * 16 + c4] = make_ushort4(f2bf(a1.x), f2bf(a1.y), f2bf(a1.z), f2bf(a1.w));
        }
    }
}

// ---------------- fused: per-bucket LDS counting sort + wide gather ----------------
__global__ __launch_bounds__(256) void gcn_bgather(const unsigned short* __restrict__ support,
                                                   const int2* __restrict__ coarse,
                                                   const int* __restrict__ gcur,
                                                   const float* __restrict__ bias,
                                                   float* __restrict__ out) {
    __shared__ int2 sE[SMAX];       // 16 KB sorted edges
    __shared__ int cntS[BN], loffS[BN], curS[BN];

    int tid = threadIdx.x, wv = tid >> 6, lane = tid & 63;
    int b = blockIdx.x;
    int tot = min(gcur[b * PAD], CAP);      // bucket edge count (post-binning cursor)
    const int2* ce = coarse + (long)b * CAP;

    if (tid < BN) cntS[tid] = 0;
    __syncthreads();

    // phase A: count per-node (bucket section is L2-warm)
    for (int e = tid; e < tot; e += 256)
        atomicAdd(&cntS[(ce[e].x >> 17) & 63], 1);
    __syncthreads();

    // scan 64 counters
    if (tid < BN) loffS[tid] = cntS[tid];
    __syncthreads();
    for (int off = 1; off < BN; off <<= 1) {
        int t = 0;
        if (tid < BN && tid >= off) t = loffS[tid - off];
        __syncthreads();
        if (tid < BN && tid >= off) loffS[tid] += t;
        __syncthreads();
    }
    if (tid < BN) {
        int excl = loffS[tid] - cntS[tid];
        loffS[tid] = excl;
        curS[tid] = excl;
    }
    __syncthreads();

    // phase B: place edges into LDS per-node-sorted (pos < tot <= SMAX always)
    for (int e = tid; e < tot; e += 256) {
        int2 ed = ce[e];
        int nl = (ed.x >> 17) & 63;
        int pos = atomicAdd(&curS[nl], 1);
        sE[pos] = ed;
    }
    __syncthreads();

    // gather: wave wv owns local nodes [wv*16, wv*16+16)
    int eg = lane >> 4;      // edge sub-slot 0..3
    int L  = lane & 15;      // feature quad 0..15
    const uint2* sup2 = (const uint2*)support;     // 8 B = 4 bf16 features
    const float4* bias4 = (const float4*)bias;
    float4* out4 = (float4*)out;
    float4 bv = bias4[L];

    for (int nl = wv * 16; nl < wv * 16 + 16; ++nl) {
        int start = loffS[nl];
        int avail = cntS[nl];
        float4 acc = make_float4(0.f, 0.f, 0.f, 0.f);
        for (int j = 0; j < avail; j += 16) {
            #pragma unroll
            for (int q = 0; q < 4; ++q) {
                int ei = j + q * 4 + eg;
                int2 ed = sE[start + min(ei, avail - 1)];
                float wgt = (ei < avail) ? __int_as_float(ed.y) : 0.f;
                uint2 p = sup2[(long)(ed.x & 0x1FFFF) * 16 + L];
                acc.x += wgt * __uint_as_float(p.x << 16);
                acc.y += wgt * __uint_as_float(p.x & 0xFFFF0000u);
                acc.z += wgt * __uint_as_float(p.y << 16);
                acc.w += wgt * __uint_as_float(p.y & 0xFFFF0000u);
            }
        }
        // reduce across the 4 edge-slot groups
        acc.x += __shfl_xor(acc.x, 16, 64); acc.y += __shfl_xor(acc.y, 16, 64);
        acc.z += __shfl_xor(acc.z, 16, 64); acc.w += __shfl_xor(acc.w, 16, 64);
        acc.x += __shfl_xor(acc.x, 32, 64); acc.y += __shfl_xor(acc.y, 32, 64);
        acc.z += __shfl_xor(acc.z, 32, 64); acc.w += __shfl_xor(acc.w, 32, 64);
        int n = b * BN + nl;
        if (lane < 16 && n < N_NODES) {
            float4 r = make_float4(acc.x + bv.x, acc.y + bv.y,
                                   acc.z + bv.z, acc.w + bv.w);
            out4[(long)n * 16 + L] = r;
        }
    }
}

// ---------------- overflow fixup (correctness only; n == 0 for this input) --------
__global__ __launch_bounds__(256) void gcn_ovffix(const int* __restrict__ ovfcnt,
                                                  const int4* __restrict__ ovflist,
                                                  const unsigned short* __restrict__ support,
                                                  float* __restrict__ out) {
    int n = *ovfcnt;
    if (n > OVFMAX) n = OVFMAX;
    int lane = threadIdx.x & 63, g = threadIdx.x >> 6;
    for (int i = g; i < n; i += 4) {
        int4 ed = ovflist[i];
        float v = __int_as_float(ed.z) * bf2f(support[(long)ed.x * D + lane]);
        atomicAdd(&out[(long)ed.y * D + lane], v);
    }
}

extern "C" void kernel_launch(void* const* d_in, const int* in_sizes, int n_in,
                              void* d_out, int out_size, void* d_ws, size_t ws_size,
                              hipStream_t stream) {
    const float* x      = (const float*)d_in[0];
    const float* weight = (const float*)d_in[1];
    const float* bias   = (const float*)d_in[2];
    const float* adj    = (const float*)d_in[3];
    const int*   src    = (const int*)d_in[4];
    const int*   dst    = (const int*)d_in[5];
    float* out = (float*)d_out;

    unsigned short* support = (unsigned short*)d_ws;          // 12,800,000 B
    int2* coarse = (int2*)(support + (long)N_NODES * D);      // NBUCK*CAP*8 = 25,608,192 B
    int*  gcur   = (int*)(coarse + (long)NBUCK * CAP);        // NBUCK*PAD*4 = 100,032 B
    int*  ovfcnt = gcur + NBUCK * PAD;                        // 16 B reserved
    int4* ovflist = (int4*)(ovfcnt + 4);                      // 524,288 B

    hipMemsetAsync(gcur, 0, NBUCK * PAD * sizeof(int) + 16, stream);
    hipLaunchKernelGGL(gcn_main, dim3(CHW + GEMM_BLKS), dim3(512), 0, stream,
                       x, weight, support, src, dst, adj, gcur, ovfcnt, ovflist, coarse);
    hipLaunchKernelGGL(gcn_bgather, dim3(NBUCK), dim3(256), 0, stream,
                       support, coarse, gcur, bias, out);
    hipLaunchKernelGGL(gcn_ovffix, dim3(1), dim3(256), 0, stream,
                       ovfcnt, ovflist, support, out);
}